// Round 1
// baseline (899.841 us; speedup 1.0000x reference)
//
#include <hip/hip_runtime.h>

#define DDIM 256
#define CHUNK 512      // nodes per block in k_pool
#define WCHUNK 128     // nodes per wave in k_pool
#define TM 64
#define TN 64
#define TK 16

// ---------------- Kernel 1: gate logits + segment max -------------------
// One wave per row (64 lanes x float4 = 256 floats). Each wave handles 8
// consecutive rows; block of 4 waves covers 32 rows.
__global__ __launch_bounds__(256) void k_gate(
    const float* __restrict__ x, const float* __restrict__ Wg,
    const float* __restrict__ bg, const int* __restrict__ index,
    float* __restrict__ gate, unsigned* __restrict__ segmax, int N)
{
    const int lane = threadIdx.x & 63;
    const int wave = threadIdx.x >> 6;
    const float4 wg = ((const float4*)Wg)[lane];
    const float b = bg[0];
    int row0 = (blockIdx.x * 4 + wave) * 8;
    for (int r = 0; r < 8; ++r) {
        int row = row0 + r;
        if (row >= N) return;                    // wave-uniform
        float4 xv = ((const float4*)x)[(size_t)row * (DDIM/4) + lane];
        float d = xv.x*wg.x + xv.y*wg.y + xv.z*wg.z + xv.w*wg.w;
        #pragma unroll
        for (int m = 32; m >= 1; m >>= 1) d += __shfl_xor(d, m, 64);
        if (lane == 0) {
            float g = d + b;
            gate[row] = g;
            unsigned bits = __float_as_uint(g);
            unsigned enc = (bits & 0x80000000u) ? ~bits : (bits | 0x80000000u);
            atomicMax(&segmax[index[row]], enc);
        }
    }
}

// ---------------- Kernel 2: w = weights^p * exp(g - m), denom ----------
__global__ __launch_bounds__(256) void k_weight(
    const float* __restrict__ weights, const float* __restrict__ p_,
    const int* __restrict__ index, const unsigned* __restrict__ segmax,
    float* __restrict__ gate, float* __restrict__ denom, int N)
{
    int i = blockIdx.x * 256 + threadIdx.x;
    if (i >= N) return;
    float p = p_[0];
    int s = index[i];
    unsigned u = segmax[s];
    unsigned bits = (u & 0x80000000u) ? (u & 0x7FFFFFFFu) : ~u;
    float m = __uint_as_float(bits);
    float w = powf(weights[i], p) * expf(gate[i] - m);
    gate[i] = w;
    atomicAdd(&denom[s], w);
}

// ---------------- Kernel 3: pooled[s,:] += gnorm_i * x[i,:] ------------
// Sorted index: each wave walks 128 contiguous nodes, keeps running float4
// accumulator per lane, flushes to pooled via atomicAdd at segment change.
__global__ __launch_bounds__(256) void k_pool(
    const float* __restrict__ x, const int* __restrict__ index,
    const float* __restrict__ gate, const float* __restrict__ denom,
    float* __restrict__ pooled, int N)
{
    __shared__ int   s_seg[CHUNK];
    __shared__ float s_g[CHUNK];
    const int n0 = blockIdx.x * CHUNK;
    for (int jj = threadIdx.x; jj < CHUNK; jj += 256) {
        int i = n0 + jj;
        if (i < N) {
            int s = index[i];
            s_seg[jj] = s;
            s_g[jj] = gate[i] / (denom[s] + 1e-10f);
        } else {
            s_seg[jj] = -1;
        }
    }
    __syncthreads();
    const int lane = threadIdx.x & 63;
    const int wave = threadIdx.x >> 6;
    const int j0 = wave * WCHUNK;
    const float4* x4 = (const float4*)x;
    float4 acc = make_float4(0.f, 0.f, 0.f, 0.f);
    int prev = -1;
    for (int j = j0; j < j0 + WCHUNK; ++j) {
        int i = n0 + j;
        if (i >= N) break;                        // wave-uniform
        int s = s_seg[j];
        if (s != prev) {                          // wave-uniform branch
            if (prev >= 0) {
                float* pp = &pooled[(size_t)prev * DDIM + lane * 4];
                atomicAdd(pp + 0, acc.x); atomicAdd(pp + 1, acc.y);
                atomicAdd(pp + 2, acc.z); atomicAdd(pp + 3, acc.w);
            }
            acc = make_float4(0.f, 0.f, 0.f, 0.f);
            prev = s;
        }
        float g = s_g[j];
        float4 xv = x4[(size_t)i * (DDIM/4) + lane];
        acc.x += g * xv.x; acc.y += g * xv.y;
        acc.z += g * xv.z; acc.w += g * xv.w;
    }
    if (prev >= 0) {
        float* pp = &pooled[(size_t)prev * DDIM + lane * 4];
        atomicAdd(pp + 0, acc.x); atomicAdd(pp + 1, acc.y);
        atomicAdd(pp + 2, acc.z); atomicAdd(pp + 3, acc.w);
    }
}

// ---------------- Kernel 4: out = pooled @ Wm + gsum*bm ----------------
// 64x64 tile, 256 threads as 16x16, 4x4 register micro-tile.
__global__ __launch_bounds__(256) void k_gemm(
    const float* __restrict__ pooled, const float* __restrict__ Wm,
    const float* __restrict__ bm, const float* __restrict__ denom,
    float* __restrict__ out, int S)
{
    __shared__ float At[TK][TM + 4];   // A transposed: At[k][r]
    __shared__ float Bs[TK][TN];
    const int tx = threadIdx.x & 15;
    const int ty = threadIdx.x >> 4;
    const int r0 = blockIdx.x * TM;
    const int c0 = blockIdx.y * TN;
    float acc[4][4] = {};

    for (int k0 = 0; k0 < DDIM; k0 += TK) {
        {   // stage A (transposed): 64 rows x 16 k; thread loads float4 along k
            int t = threadIdx.x;
            int r = t >> 2;
            int kq = (t & 3) * 4;
            float4 a = make_float4(0.f, 0.f, 0.f, 0.f);
            if (r0 + r < S)
                a = *(const float4*)&pooled[(size_t)(r0 + r) * DDIM + k0 + kq];
            At[kq + 0][r] = a.x; At[kq + 1][r] = a.y;
            At[kq + 2][r] = a.z; At[kq + 3][r] = a.w;
        }
        {   // stage B: 16 k x 64 cols
            int t = threadIdx.x;
            int k = t >> 4;
            int cq = (t & 15) * 4;
            float4 bv = *(const float4*)&Wm[(size_t)(k0 + k) * DDIM + c0 + cq];
            *(float4*)&Bs[k][cq] = bv;
        }
        __syncthreads();
        #pragma unroll
        for (int k = 0; k < TK; ++k) {
            const float4 av = *(const float4*)&At[k][ty * 4];
            const float4 bv = *(const float4*)&Bs[k][tx * 4];
            float a4[4] = {av.x, av.y, av.z, av.w};
            float b4[4] = {bv.x, bv.y, bv.z, bv.w};
            #pragma unroll
            for (int i = 0; i < 4; ++i)
                #pragma unroll
                for (int j = 0; j < 4; ++j)
                    acc[i][j] += a4[i] * b4[j];
        }
        __syncthreads();
    }

    const float4 bmv = *(const float4*)&bm[c0 + tx * 4];
    #pragma unroll
    for (int i = 0; i < 4; ++i) {
        int row = r0 + ty * 4 + i;
        if (row >= S) continue;
        float dn = denom[row];
        float gs = dn / (dn + 1e-10f);
        float4 o;
        o.x = acc[i][0] + gs * bmv.x;
        o.y = acc[i][1] + gs * bmv.y;
        o.z = acc[i][2] + gs * bmv.z;
        o.w = acc[i][3] + gs * bmv.w;
        *(float4*)&out[(size_t)row * DDIM + c0 + tx * 4] = o;
    }
}

extern "C" void kernel_launch(void* const* d_in, const int* in_sizes, int n_in,
                              void* d_out, int out_size, void* d_ws, size_t ws_size,
                              hipStream_t stream) {
    const float* x       = (const float*)d_in[0];
    const float* weights = (const float*)d_in[1];
    const float* Wg      = (const float*)d_in[2];
    const float* bg      = (const float*)d_in[3];
    const float* Wm      = (const float*)d_in[4];
    const float* bm      = (const float*)d_in[5];
    const float* p       = (const float*)d_in[6];
    const int*   index   = (const int*)d_in[7];

    const int N = in_sizes[1];        // weights is (N,1)
    const int D = in_sizes[2];        // Wg is (D,1) -> 256
    const int S = out_size / D;
    float* out = (float*)d_out;

    float*    gate   = (float*)d_ws;
    unsigned* segmax = (unsigned*)(gate + N);
    float*    denom  = (float*)(segmax + S);
    float*    pooled = denom + S;

    hipMemsetAsync(segmax, 0, (size_t)S * sizeof(unsigned), stream);  // 0 == -inf encoded
    hipMemsetAsync(denom,  0, (size_t)S * sizeof(float), stream);
    hipMemsetAsync(pooled, 0, (size_t)S * D * sizeof(float), stream);

    k_gate  <<<(N + 31) / 32,        256, 0, stream>>>(x, Wg, bg, index, gate, segmax, N);
    k_weight<<<(N + 255) / 256,      256, 0, stream>>>(weights, p, index, segmax, gate, denom, N);
    k_pool  <<<(N + CHUNK-1)/CHUNK,  256, 0, stream>>>(x, index, gate, denom, pooled, N);

    dim3 g5((S + TM - 1) / TM, D / TN);
    k_gemm  <<<g5, 256, 0, stream>>>(pooled, Wm, bm, denom, out, S);
}

// Round 2
// 749.915 us; speedup vs baseline: 1.1999x; 1.1999x over previous
//
#include <hip/hip_runtime.h>
#include <math.h>

#define DDIM 256
#define CHUNK 512      // nodes per block in fused kernel
#define WCHUNK 128     // nodes per wave
#define TM 64
#define TN 64
#define TK 32

// ---- Fused kernel: gate dot + w^p*exp + segment pooling, ONE pass over x --
// Block = 256 threads = 4 waves; each wave walks 128 consecutive (sorted)
// nodes. Per node: load row (64 lanes x float4), dot with Wg, butterfly
// reduce (sum lands on all lanes), w = weights^p * exp(gate), accumulate
// w*x into a running per-lane float4; flush to pooled[] via atomicAdd only
// at segment boundaries. denom accumulated alongside.
__global__ __launch_bounds__(256) void k_fused(
    const float* __restrict__ x, const float* __restrict__ weights,
    const float* __restrict__ Wg, const float* __restrict__ bg,
    const float* __restrict__ p_, const int* __restrict__ index,
    float* __restrict__ pooled, float* __restrict__ denom, int N)
{
    __shared__ int   s_seg[CHUNK];
    __shared__ float s_wp[CHUNK];
    const int n0 = blockIdx.x * CHUNK;
    const float p = p_[0];
    for (int jj = threadIdx.x; jj < CHUNK; jj += 256) {
        int i = n0 + jj;
        if (i < N) {
            s_seg[jj] = index[i];
            s_wp[jj]  = powf(weights[i], p);
        } else {
            s_seg[jj] = -1;
        }
    }
    __syncthreads();

    const int lane = threadIdx.x & 63;
    const int wave = threadIdx.x >> 6;
    const float4 wg = ((const float4*)Wg)[lane];
    const float b = bg[0];
    const int j0 = wave * WCHUNK;
    const float4* x4 = (const float4*)x;

    float4 acc = make_float4(0.f, 0.f, 0.f, 0.f);
    float wsum = 0.f;
    int prev = -1;

    for (int j = j0; j < j0 + WCHUNK; ++j) {
        int i = n0 + j;
        if (i >= N) break;                       // wave-uniform
        int s = s_seg[j];
        if (s != prev) {                         // wave-uniform (sorted index)
            if (prev >= 0) {
                float* pp = &pooled[(size_t)prev * DDIM + lane * 4];
                atomicAdd(pp + 0, acc.x); atomicAdd(pp + 1, acc.y);
                atomicAdd(pp + 2, acc.z); atomicAdd(pp + 3, acc.w);
                if (lane == 0) atomicAdd(&denom[prev], wsum);
            }
            acc = make_float4(0.f, 0.f, 0.f, 0.f);
            wsum = 0.f;
            prev = s;
        }
        float4 xv = x4[(size_t)i * (DDIM/4) + lane];
        float d = xv.x*wg.x + xv.y*wg.y + xv.z*wg.z + xv.w*wg.w;
        #pragma unroll
        for (int m = 32; m >= 1; m >>= 1) d += __shfl_xor(d, m, 64);
        float w = s_wp[j] * __expf(d + b);       // exp(gate), no max-sub needed
        acc.x += w * xv.x; acc.y += w * xv.y;
        acc.z += w * xv.z; acc.w += w * xv.w;
        wsum += w;
    }
    if (prev >= 0) {
        float* pp = &pooled[(size_t)prev * DDIM + lane * 4];
        atomicAdd(pp + 0, acc.x); atomicAdd(pp + 1, acc.y);
        atomicAdd(pp + 2, acc.z); atomicAdd(pp + 3, acc.w);
        if (lane == 0) atomicAdd(&denom[prev], wsum);
    }
}

// ---- GEMM: out = (pooledU @ Wm) * scale + bm * (denom*scale) --------------
// scale_s = 1/(denom_s + 1e-10) applied in the epilogue (normalization is a
// per-row scalar, commutes with the linear map). 64x64 tile, 4x4 micro.
__global__ __launch_bounds__(256) void k_gemm(
    const float* __restrict__ pooled, const float* __restrict__ Wm,
    const float* __restrict__ bm, const float* __restrict__ denom,
    float* __restrict__ out, int S)
{
    __shared__ float At[TK][TM + 4];   // A transposed: At[k][r]
    __shared__ float Bs[TK][TN];
    const int tx = threadIdx.x & 15;
    const int ty = threadIdx.x >> 4;
    const int r0 = blockIdx.x * TM;
    const int c0 = blockIdx.y * TN;
    float acc[4][4] = {};

    for (int k0 = 0; k0 < DDIM; k0 += TK) {
        #pragma unroll
        for (int it = 0; it < 2; ++it) {
            int idx = threadIdx.x + it * 256;
            {   // stage A transposed: 64 rows x 32 k
                int r  = idx >> 3;
                int kq = (idx & 7) * 4;
                float4 a = make_float4(0.f, 0.f, 0.f, 0.f);
                if (r0 + r < S)
                    a = *(const float4*)&pooled[(size_t)(r0 + r) * DDIM + k0 + kq];
                At[kq + 0][r] = a.x; At[kq + 1][r] = a.y;
                At[kq + 2][r] = a.z; At[kq + 3][r] = a.w;
            }
            {   // stage B: 32 k x 64 cols
                int k  = idx >> 4;
                int cq = (idx & 15) * 4;
                *(float4*)&Bs[k][cq] =
                    *(const float4*)&Wm[(size_t)(k0 + k) * DDIM + c0 + cq];
            }
        }
        __syncthreads();
        #pragma unroll
        for (int k = 0; k < TK; ++k) {
            const float4 av = *(const float4*)&At[k][ty * 4];
            const float4 bv = *(const float4*)&Bs[k][tx * 4];
            float a4[4] = {av.x, av.y, av.z, av.w};
            float b4[4] = {bv.x, bv.y, bv.z, bv.w};
            #pragma unroll
            for (int i = 0; i < 4; ++i)
                #pragma unroll
                for (int j = 0; j < 4; ++j)
                    acc[i][j] += a4[i] * b4[j];
        }
        __syncthreads();
    }

    const float4 bmv = *(const float4*)&bm[c0 + tx * 4];
    #pragma unroll
    for (int i = 0; i < 4; ++i) {
        int row = r0 + ty * 4 + i;
        if (row >= S) continue;
        float dn = denom[row];
        float scale = 1.f / (dn + 1e-10f);
        float gs = dn * scale;
        float4 o;
        o.x = acc[i][0] * scale + gs * bmv.x;
        o.y = acc[i][1] * scale + gs * bmv.y;
        o.z = acc[i][2] * scale + gs * bmv.z;
        o.w = acc[i][3] * scale + gs * bmv.w;
        *(float4*)&out[(size_t)row * DDIM + c0 + tx * 4] = o;
    }
}

extern "C" void kernel_launch(void* const* d_in, const int* in_sizes, int n_in,
                              void* d_out, int out_size, void* d_ws, size_t ws_size,
                              hipStream_t stream) {
    const float* x       = (const float*)d_in[0];
    const float* weights = (const float*)d_in[1];
    const float* Wg      = (const float*)d_in[2];
    const float* bg      = (const float*)d_in[3];
    const float* Wm      = (const float*)d_in[4];
    const float* bm      = (const float*)d_in[5];
    const float* p       = (const float*)d_in[6];
    const int*   index   = (const int*)d_in[7];

    const int N = in_sizes[1];        // weights is (N,1)
    const int D = in_sizes[2];        // Wg is (D,1) -> 256
    const int S = out_size / D;
    float* out = (float*)d_out;

    float* denom  = (float*)d_ws;
    float* pooled = denom + S;

    hipMemsetAsync(denom,  0, (size_t)S * sizeof(float), stream);
    hipMemsetAsync(pooled, 0, (size_t)S * D * sizeof(float), stream);

    k_fused<<<(N + CHUNK - 1) / CHUNK, 256, 0, stream>>>(
        x, weights, Wg, bg, p, index, pooled, denom, N);

    dim3 g2((S + TM - 1) / TM, D / TN);
    k_gemm<<<g2, 256, 0, stream>>>(pooled, Wm, bm, denom, out, S);
}